// Round 6
// baseline (2968.784 us; speedup 1.0000x reference)
//
#include <hip/hip_runtime.h>

typedef _Float16 half8 __attribute__((ext_vector_type(8)));
typedef float    float4v __attribute__((ext_vector_type(4)));

#define NQ 8
#define KCODES 4096
#define DIMS 128
#define BATCH 8
#define SEQ 4096
#define ROWS (BATCH*SEQ)            // 32768
#define TM 64                       // rows per block
#define NBLK (ROWS/TM)              // 512
#define RESPAD 132                  // res row stride (floats), 16B-aligned
#define OUT_ELEMS (BATCH*DIMS*SEQ)  // 4194304
#define IDX_ELEMS (BATCH*SEQ*NQ)    // 262144
#define LOSS_DIV (1.0f/33554432.0f) // 1/(Q*B*N*D)
#define FRAG_HALVES ((size_t)NQ*4*256*64*8)   // per hi/lo: 4.19M f16 = 8 MB

// ---------------- prep: c_sq[q][k] = sum_d cb^2 ----------------
__global__ void prep_csq(const float* __restrict__ cb, float* __restrict__ csq) {
    int c = blockIdx.x * 256 + threadIdx.x;   // q*4096+k
    const float4* p = (const float4*)(cb + (size_t)c * DIMS);
    float s = 0.f;
#pragma unroll
    for (int i = 0; i < 32; ++i) {
        float4 v = p[i];
        s += v.x * v.x + v.y * v.y + v.z * v.z + v.w * v.w;
    }
    csq[c] = s;
}

// ---------------- prep: codebook -> f16 hi/lo MFMA B-fragments ----------------
// mfma_f32_16x16x32_f16 B-operand: lane l holds B[k=(l>>4)*8+j][n=l&15], j=0..7.
// Storage: frag g = ((q*4+kb)*256+nt)*64+lane at bhi/blo + g*8 halves.
__global__ void prep_frags(const float* __restrict__ cb, _Float16* __restrict__ bhi,
                           _Float16* __restrict__ blo, float* __restrict__ loss_accum) {
    int g = blockIdx.x * 256 + threadIdx.x;   // 524288 total
    if (g == 0) loss_accum[0] = 0.f;
    int lane = g & 63;
    int nt   = (g >> 6) & 255;
    int kb   = (g >> 14) & 3;
    int q    = g >> 16;
    int code = nt * 16 + (lane & 15);
    int k0   = kb * 32 + ((lane >> 4) * 8);
    const float* src = cb + ((size_t)q * KCODES + code) * DIMS + k0;
    float4 v0 = *(const float4*)(src);
    float4 v1 = *(const float4*)(src + 4);
    float f[8] = { v0.x, v0.y, v0.z, v0.w, v1.x, v1.y, v1.z, v1.w };
    half8 h, l;
#pragma unroll
    for (int j = 0; j < 8; ++j) {
        _Float16 hh = (_Float16)f[j];
        h[j] = hh;
        l[j] = (_Float16)(f[j] - (float)hh);
    }
    *(half8*)(bhi + (size_t)g * 8) = h;
    *(half8*)(blo + (size_t)g * 8) = l;
}

// ---------------- main RVQ kernel ----------------
__device__ __forceinline__ void load_b(const _Float16* __restrict__ bq_hi,
                                       const _Float16* __restrict__ bq_lo,
                                       const float* __restrict__ csqq,
                                       int nt, int lane,
                                       half8 (&bh)[4], half8 (&bl)[4], float& cs) {
#pragma unroll
    for (int kb = 0; kb < 4; ++kb) {
        size_t off = (((size_t)kb * 256 + nt) * 64 + lane) * 8;
        bh[kb] = *(const half8*)(bq_hi + off);
        bl[kb] = *(const half8*)(bq_lo + off);
    }
    cs = csqq[nt * 16 + (lane & 15)];
}

// argmin over a half (mt range) of a finished accumulator set.
// key = acc value (csq/2 already folded in via init); strict > == first-index.
__device__ __forceinline__ void argmin_half(const float4v (&accP)[4], int mt0, float fidxP,
                                            float (&bestd)[4][4], float (&besti)[4][4]) {
#pragma unroll
    for (int mt = mt0; mt < mt0 + 2; ++mt)
#pragma unroll
        for (int r = 0; r < 4; ++r) {
            float key = accP[mt][r];
            if (key > bestd[mt][r]) { bestd[mt][r] = key; besti[mt][r] = fidxP; }
        }
}

// Pipelined tile: emit this tile's 48 MFMAs (term-major, same-acc distance 4)
// with the PREVIOUS tile's argmin VALU interleaved between term groups so it
// can issue in the MFMA pipe's shadow. accP rows are disjoint slots updated in
// ascending-tile order per slot -> tie-break semantics identical.
template <bool DOPREV>
__device__ __forceinline__ void tile_pipe(float4v (&acc)[4],
                                          const half8 (&ahi)[4][4], const half8 (&alo)[4][4],
                                          const half8 (&bh)[4], const half8 (&bl)[4], float cs,
                                          const float4v (&accP)[4], float fidxP,
                                          float (&bestd)[4][4], float (&besti)[4][4]) {
    float nh = -0.5f * cs;
#pragma unroll
    for (int mt = 0; mt < 4; ++mt) { acc[mt][0] = nh; acc[mt][1] = nh; acc[mt][2] = nh; acc[mt][3] = nh; }
#pragma unroll
    for (int kb = 0; kb < 4; ++kb)
#pragma unroll
        for (int mt = 0; mt < 4; ++mt)
            acc[mt] = __builtin_amdgcn_mfma_f32_16x16x32_f16(ahi[mt][kb], bh[kb], acc[mt], 0, 0, 0);
    if (DOPREV) argmin_half(accP, 0, fidxP, bestd, besti);
#pragma unroll
    for (int kb = 0; kb < 4; ++kb)
#pragma unroll
        for (int mt = 0; mt < 4; ++mt)
            acc[mt] = __builtin_amdgcn_mfma_f32_16x16x32_f16(alo[mt][kb], bh[kb], acc[mt], 0, 0, 0);
    if (DOPREV) argmin_half(accP, 2, fidxP, bestd, besti);
#pragma unroll
    for (int kb = 0; kb < 4; ++kb)
#pragma unroll
        for (int mt = 0; mt < 4; ++mt)
            acc[mt] = __builtin_amdgcn_mfma_f32_16x16x32_f16(ahi[mt][kb], bl[kb], acc[mt], 0, 0, 0);
}

__launch_bounds__(256, 2)
__global__ void rvq_main(const float* __restrict__ x, const float* __restrict__ cb,
                         const _Float16* __restrict__ bhi, const _Float16* __restrict__ blo,
                         const float* __restrict__ csq,
                         float* __restrict__ out, float* __restrict__ loss_accum) {
    __shared__ float res[TM][RESPAD];   // residual, row-major fp32
    __shared__ float wbd[4][TM];        // per-wave best key
    __shared__ float wbi[4][TM];        // per-wave best idx (as float)
    __shared__ float fbin[TM];          // final best idx per row
    __shared__ float red[256];

    int tid  = threadIdx.x;
    int lane = tid & 63;
    int wv   = tid >> 6;
    int r0   = blockIdx.x * TM;
    int b    = r0 >> 12;                // / SEQ
    int n0   = r0 & (SEQ - 1);
    const float* xb = x + (size_t)b * DIMS * SEQ + n0;
    float fcol = (float)(lane & 15);

    // load x[b][d][n0..n0+63] into res[n][d]
    {
        int d = tid >> 1, half = (tid & 1) * 32;
        const float* src = xb + (size_t)d * SEQ + half;
#pragma unroll
        for (int t4 = 0; t4 < 8; ++t4) {
            float4 v = *(const float4*)(src + t4 * 4);
            res[half + t4 * 4 + 0][d] = v.x;
            res[half + t4 * 4 + 1][d] = v.y;
            res[half + t4 * 4 + 2][d] = v.z;
            res[half + t4 * 4 + 3][d] = v.w;
        }
    }

    float lossacc = 0.f;

    for (int q = 0; q < NQ; ++q) {
        __syncthreads();   // res stable

        // build A fragments (hi/lo) in registers/AGPRs
        half8 ahi[4][4], alo[4][4];
#pragma unroll
        for (int mt = 0; mt < 4; ++mt)
#pragma unroll
        for (int kb = 0; kb < 4; ++kb) {
            int row = mt * 16 + (lane & 15);
            int k0  = kb * 32 + (lane >> 4) * 8;
            float4 v0 = *(const float4*)&res[row][k0];
            float4 v1 = *(const float4*)&res[row][k0 + 4];
            float f[8] = { v0.x, v0.y, v0.z, v0.w, v1.x, v1.y, v1.z, v1.w };
            half8 h, l;
#pragma unroll
            for (int j = 0; j < 8; ++j) {
                _Float16 hh = (_Float16)f[j];
                h[j] = hh;
                l[j] = (_Float16)(f[j] - (float)hh);
            }
            ahi[mt][kb] = h;
            alo[mt][kb] = l;
        }

        const _Float16* bq_hi = bhi + (size_t)q * (4 * 256 * 64 * 8);
        const _Float16* bq_lo = blo + (size_t)q * (4 * 256 * 64 * 8);
        const float*    csqq  = csq + q * KCODES;

        float bestd[4][4], besti[4][4];
#pragma unroll
        for (int mt = 0; mt < 4; ++mt)
#pragma unroll
        for (int r = 0; r < 4; ++r) { bestd[mt][r] = -3.4e38f; besti[mt][r] = 0.f; }

        // each wave owns n-tiles [wv*64, wv*64+64)
        // B double-buffered; acc double-buffered for argmin pipelining
        int ntBase = wv * 64;
        half8 bh0[4], bl0[4], bh1[4], bl1[4];
        float cs0, cs1;
        float4v accA[4], accB[4];
        float fiA, fiB;

        load_b(bq_hi, bq_lo, csqq, ntBase + 0, lane, bh0, bl0, cs0);
        load_b(bq_hi, bq_lo, csqq, ntBase + 1, lane, bh1, bl1, cs1);
        fiA = (float)((ntBase + 0) * 16) + fcol;
        tile_pipe<false>(accA, ahi, alo, bh0, bl0, cs0, accB, 0.f, bestd, besti);  // t0

        for (int i = 1; i < 63; i += 2) {
            load_b(bq_hi, bq_lo, csqq, ntBase + i + 1, lane, bh0, bl0, cs0);
            fiB = (float)((ntBase + i) * 16) + fcol;
            tile_pipe<true>(accB, ahi, alo, bh1, bl1, cs1, accA, fiA, bestd, besti);  // t_i, argmin t_{i-1}
            load_b(bq_hi, bq_lo, csqq, ntBase + i + 2, lane, bh1, bl1, cs1);
            fiA = (float)((ntBase + i + 1) * 16) + fcol;
            tile_pipe<true>(accA, ahi, alo, bh0, bl0, cs0, accB, fiB, bestd, besti);  // t_{i+1}, argmin t_i
        }
        // tail: t63 (in buf1), argmin t62 (accA), then argmin t63
        fiB = (float)((ntBase + 63) * 16) + fcol;
        tile_pipe<true>(accB, ahi, alo, bh1, bl1, cs1, accA, fiA, bestd, besti);
        argmin_half(accB, 0, fiB, bestd, besti);
        argmin_half(accB, 2, fiB, bestd, besti);

        // reduce across the 16 lanes sharing each row (low 4 lane bits)
#pragma unroll
        for (int mask = 1; mask <= 8; mask <<= 1) {
#pragma unroll
            for (int mt = 0; mt < 4; ++mt)
#pragma unroll
            for (int r = 0; r < 4; ++r) {
                float od = __shfl_xor(bestd[mt][r], mask, 64);
                float oi = __shfl_xor(besti[mt][r], mask, 64);
                if (od > bestd[mt][r] || (od == bestd[mt][r] && oi < besti[mt][r])) {
                    bestd[mt][r] = od;
                    besti[mt][r] = oi;
                }
            }
        }
        if ((lane & 15) == 0) {
            int qd = lane >> 4;
#pragma unroll
            for (int mt = 0; mt < 4; ++mt)
#pragma unroll
            for (int r = 0; r < 4; ++r) {
                int row = mt * 16 + qd * 4 + r;
                wbd[wv][row] = bestd[mt][r];
                wbi[wv][row] = besti[mt][r];
            }
        }
        __syncthreads();

        // cross-wave reduce (waves cover ascending code ranges; tie -> smaller idx)
        if (tid < TM) {
            float bd = wbd[0][tid], bi = wbi[0][tid];
#pragma unroll
            for (int w = 1; w < 4; ++w) {
                float dd = wbd[w][tid], ii = wbi[w][tid];
                if (dd > bd || (dd == bd && ii < bi)) { bd = dd; bi = ii; }
            }
            fbin[tid] = bi;
            out[OUT_ELEMS + (size_t)(r0 + tid) * NQ + q] = bi;   // index output (float)
        }
        __syncthreads();

        // residual update + commitment-loss accumulation
        {
            int row = tid >> 2, j = tid & 3;
            int bi = (int)fbin[row];
            const float* cv = cb + ((size_t)q * KCODES + bi) * DIMS + j * 4;
            float* rp = &res[row][j * 4];
#pragma unroll
            for (int t = 0; t < 8; ++t) {
                float4 c4 = *(const float4*)(cv + t * 16);
                float4 r4 = *(const float4*)(rp + t * 16);
                r4.x -= c4.x; lossacc = fmaf(r4.x, r4.x, lossacc);
                r4.y -= c4.y; lossacc = fmaf(r4.y, r4.y, lossacc);
                r4.z -= c4.z; lossacc = fmaf(r4.z, r4.z, lossacc);
                r4.w -= c4.w; lossacc = fmaf(r4.w, r4.w, lossacc);
                *(float4*)(rp + t * 16) = r4;
            }
        }
    }

    // loss reduction
    __syncthreads();
    red[tid] = lossacc;
    __syncthreads();
    for (int s = 128; s > 0; s >>= 1) {
        if (tid < s) red[tid] += red[tid + s];
        __syncthreads();
    }
    if (tid == 0) atomicAdd(loss_accum, red[0]);

    // quantized output: out = x - final_residual
    {
        int d = tid >> 1, half = (tid & 1) * 32;
        const float* src = xb + (size_t)d * SEQ + half;
        float* dst = out + (size_t)b * DIMS * SEQ + (size_t)d * SEQ + n0 + half;
#pragma unroll
        for (int t4 = 0; t4 < 8; ++t4) {
            float4 v = *(const float4*)(src + t4 * 4);
            v.x -= res[half + t4 * 4 + 0][d];
            v.y -= res[half + t4 * 4 + 1][d];
            v.z -= res[half + t4 * 4 + 2][d];
            v.w -= res[half + t4 * 4 + 3][d];
            *(float4*)(dst + t4 * 4) = v;
        }
    }
}

__global__ void finish_loss(const float* __restrict__ loss_accum, float* __restrict__ out) {
    out[OUT_ELEMS + IDX_ELEMS] = loss_accum[0] * LOSS_DIV;
}

extern "C" void kernel_launch(void* const* d_in, const int* in_sizes, int n_in,
                              void* d_out, int out_size, void* d_ws, size_t ws_size,
                              hipStream_t stream) {
    const float* x  = (const float*)d_in[0];
    const float* cb = (const float*)d_in[1];
    float* out = (float*)d_out;
    char*  ws  = (char*)d_ws;

    float*     loss_accum = (float*)ws;
    float*     csq = (float*)(ws + 256);
    _Float16*  bhi = (_Float16*)(ws + 256 + 131072);
    _Float16*  blo = (_Float16*)(ws + 256 + 131072 + FRAG_HALVES * 2);

    hipLaunchKernelGGL(prep_csq,   dim3(128),  dim3(256), 0, stream, cb, csq);
    hipLaunchKernelGGL(prep_frags, dim3(2048), dim3(256), 0, stream, cb, bhi, blo, loss_accum);
    hipLaunchKernelGGL(rvq_main,   dim3(NBLK), dim3(256), 0, stream,
                       x, cb, bhi, blo, csq, out, loss_accum);
    hipLaunchKernelGGL(finish_loss, dim3(1), dim3(1), 0, stream, loss_accum, out);
}

// Round 7
// 1206.221 us; speedup vs baseline: 2.4612x; 2.4612x over previous
//
#include <hip/hip_runtime.h>

typedef _Float16 half8 __attribute__((ext_vector_type(8)));
typedef float    float4v __attribute__((ext_vector_type(4)));

#define NQ 8
#define KCODES 4096
#define DIMS 128
#define BATCH 8
#define SEQ 4096
#define ROWS (BATCH*SEQ)            // 32768
#define TM 64                       // rows per block
#define NBLK (ROWS/TM)              // 512
#define RESPAD 132                  // res row stride (floats), 16B-aligned
#define OUT_ELEMS (BATCH*DIMS*SEQ)  // 4194304
#define IDX_ELEMS (BATCH*SEQ*NQ)    // 262144
#define LOSS_DIV (1.0f/33554432.0f) // 1/(Q*B*N*D)
#define FRAG_HALVES ((size_t)NQ*4*256*64*8)   // per hi/lo: 4.19M f16 = 8 MB

// ---------------- prep: c_sq[q][k] = sum_d cb^2 ----------------
__global__ void prep_csq(const float* __restrict__ cb, float* __restrict__ csq) {
    int c = blockIdx.x * 256 + threadIdx.x;   // q*4096+k
    const float4* p = (const float4*)(cb + (size_t)c * DIMS);
    float s = 0.f;
#pragma unroll
    for (int i = 0; i < 32; ++i) {
        float4 v = p[i];
        s += v.x * v.x + v.y * v.y + v.z * v.z + v.w * v.w;
    }
    csq[c] = s;
}

// ---------------- prep: codebook -> f16 hi/lo MFMA B-fragments ----------------
// mfma_f32_16x16x32_f16 B-operand: lane l holds B[k=(l>>4)*8+j][n=l&15], j=0..7.
// Storage: frag g = ((q*4+kb)*256+nt)*64+lane at bhi/blo + g*8 halves.
__global__ void prep_frags(const float* __restrict__ cb, _Float16* __restrict__ bhi,
                           _Float16* __restrict__ blo, float* __restrict__ loss_accum) {
    int g = blockIdx.x * 256 + threadIdx.x;   // 524288 total
    if (g == 0) loss_accum[0] = 0.f;
    int lane = g & 63;
    int nt   = (g >> 6) & 255;
    int kb   = (g >> 14) & 3;
    int q    = g >> 16;
    int code = nt * 16 + (lane & 15);
    int k0   = kb * 32 + ((lane >> 4) * 8);
    const float* src = cb + ((size_t)q * KCODES + code) * DIMS + k0;
    float4 v0 = *(const float4*)(src);
    float4 v1 = *(const float4*)(src + 4);
    float f[8] = { v0.x, v0.y, v0.z, v0.w, v1.x, v1.y, v1.z, v1.w };
    half8 h, l;
#pragma unroll
    for (int j = 0; j < 8; ++j) {
        _Float16 hh = (_Float16)f[j];
        h[j] = hh;
        l[j] = (_Float16)(f[j] - (float)hh);
    }
    *(half8*)(bhi + (size_t)g * 8) = h;
    *(half8*)(blo + (size_t)g * 8) = l;
}

// ---------------- main RVQ kernel ----------------
__device__ __forceinline__ void load_bh(const _Float16* __restrict__ bq_hi,
                                        const float* __restrict__ csqq,
                                        int nt, int lane, half8 (&bh)[4], float& cs) {
#pragma unroll
    for (int kb = 0; kb < 4; ++kb)
        bh[kb] = *(const half8*)(bq_hi + (((size_t)kb * 256 + nt) * 64 + lane) * 8);
    cs = csqq[nt * 16 + (lane & 15)];
}

__device__ __forceinline__ void load_bl(const _Float16* __restrict__ bq_lo,
                                        int nt, int lane, half8 (&bl)[4]) {
#pragma unroll
    for (int kb = 0; kb < 4; ++kb)
        bl[kb] = *(const half8*)(bq_lo + (((size_t)kb * 256 + nt) * 64 + lane) * 8);
}

// argmin of 8 slots (2 mt rows) of the finished accP. strict > == first-index.
__device__ __forceinline__ void argmin_pair(const float4v (&accP)[4], int mt0, float fidxP,
                                            float (&bestd)[4][4], float (&besti)[4][4]) {
#pragma unroll
    for (int mt = mt0; mt < mt0 + 2; ++mt)
#pragma unroll
        for (int r = 0; r < 4; ++r) {
            float key = accP[mt][r];
            if (key > bestd[mt][r]) { bestd[mt][r] = key; besti[mt][r] = fidxP; }
        }
}

// Pipelined tile: 48 MFMAs (term-major, same-acc distance 4) with the PREVIOUS
// tile's 48-inst argmin interleaved as 12-inst chunks after every second
// kb-subgroup (~1.5 VALU per MFMA locally) so each wave's own issue slots feed
// the VALU pipe while the MFMA pipe grinds — works even when the 2 waves/SIMD
// are phase-locked. accP slots are updated in ascending-tile order -> tie-break
// semantics identical to a serial scan.
template <bool DOPREV>
__device__ __forceinline__ void tile_pipe(float4v (&acc)[4],
                                          const half8 (&ahi)[4][4], const half8 (&alo)[4][4],
                                          const half8 (&bh)[4], const half8 (&bl)[4], float cs,
                                          const float4v (&accP)[4], float fidxP,
                                          float (&bestd)[4][4], float (&besti)[4][4]) {
    float nh = -0.5f * cs;
#pragma unroll
    for (int mt = 0; mt < 4; ++mt) { acc[mt][0] = nh; acc[mt][1] = nh; acc[mt][2] = nh; acc[mt][3] = nh; }

    // hh group: kb subgroups of 4 MFMAs; argmin chunks after kb1, kb3
#pragma unroll
    for (int kb = 0; kb < 4; ++kb) {
#pragma unroll
        for (int mt = 0; mt < 4; ++mt)
            acc[mt] = __builtin_amdgcn_mfma_f32_16x16x32_f16(ahi[mt][kb], bh[kb], acc[mt], 0, 0, 0);
        if (DOPREV && kb == 1) argmin_pair(accP, 0, fidxP, bestd, besti);
        if (DOPREV && kb == 3) argmin_pair(accP, 2, fidxP, bestd, besti);
    }
    // lh group (no interleave: argmin budget spent; pipe stays fed via 2 waves)
#pragma unroll
    for (int kb = 0; kb < 4; ++kb)
#pragma unroll
        for (int mt = 0; mt < 4; ++mt)
            acc[mt] = __builtin_amdgcn_mfma_f32_16x16x32_f16(alo[mt][kb], bh[kb], acc[mt], 0, 0, 0);
    // hl group (reads bl)
#pragma unroll
    for (int kb = 0; kb < 4; ++kb)
#pragma unroll
        for (int mt = 0; mt < 4; ++mt)
            acc[mt] = __builtin_amdgcn_mfma_f32_16x16x32_f16(ahi[mt][kb], bl[kb], acc[mt], 0, 0, 0);
}

__launch_bounds__(256, 2)
__global__ void rvq_main(const float* __restrict__ x, const float* __restrict__ cb,
                         const _Float16* __restrict__ bhi, const _Float16* __restrict__ blo,
                         const float* __restrict__ csq,
                         float* __restrict__ out, float* __restrict__ loss_accum) {
    __shared__ float res[TM][RESPAD];   // residual, row-major fp32
    __shared__ float wbd[4][TM];        // per-wave best key
    __shared__ float wbi[4][TM];        // per-wave best idx (as float)
    __shared__ float fbin[TM];          // final best idx per row
    __shared__ float red[256];

    int tid  = threadIdx.x;
    int lane = tid & 63;
    int wv   = tid >> 6;
    int r0   = blockIdx.x * TM;
    int b    = r0 >> 12;                // / SEQ
    int n0   = r0 & (SEQ - 1);
    const float* xb = x + (size_t)b * DIMS * SEQ + n0;
    float fcol = (float)(lane & 15);

    // load x[b][d][n0..n0+63] into res[n][d]
    {
        int d = tid >> 1, half = (tid & 1) * 32;
        const float* src = xb + (size_t)d * SEQ + half;
#pragma unroll
        for (int t4 = 0; t4 < 8; ++t4) {
            float4 v = *(const float4*)(src + t4 * 4);
            res[half + t4 * 4 + 0][d] = v.x;
            res[half + t4 * 4 + 1][d] = v.y;
            res[half + t4 * 4 + 2][d] = v.z;
            res[half + t4 * 4 + 3][d] = v.w;
        }
    }

    float lossacc = 0.f;

    for (int q = 0; q < NQ; ++q) {
        __syncthreads();   // res stable

        // build A fragments (hi/lo) in registers/AGPRs
        half8 ahi[4][4], alo[4][4];
#pragma unroll
        for (int mt = 0; mt < 4; ++mt)
#pragma unroll
        for (int kb = 0; kb < 4; ++kb) {
            int row = mt * 16 + (lane & 15);
            int k0  = kb * 32 + (lane >> 4) * 8;
            float4 v0 = *(const float4*)&res[row][k0];
            float4 v1 = *(const float4*)&res[row][k0 + 4];
            float f[8] = { v0.x, v0.y, v0.z, v0.w, v1.x, v1.y, v1.z, v1.w };
            half8 h, l;
#pragma unroll
            for (int j = 0; j < 8; ++j) {
                _Float16 hh = (_Float16)f[j];
                h[j] = hh;
                l[j] = (_Float16)(f[j] - (float)hh);
            }
            ahi[mt][kb] = h;
            alo[mt][kb] = l;
        }

        const _Float16* bq_hi = bhi + (size_t)q * (4 * 256 * 64 * 8);
        const _Float16* bq_lo = blo + (size_t)q * (4 * 256 * 64 * 8);
        const float*    csqq  = csq + q * KCODES;

        float bestd[4][4], besti[4][4];
#pragma unroll
        for (int mt = 0; mt < 4; ++mt)
#pragma unroll
        for (int r = 0; r < 4; ++r) { bestd[mt][r] = -3.4e38f; besti[mt][r] = 0.f; }

        // each wave owns n-tiles [wv*64, wv*64+64)
        // bh: double-buffered (dist 1 tile). bl: deferred single buffer — loaded
        // right after this tile's hl group issues (WAR-safe), consumed by the
        // NEXT tile's hl group (~32 MFMAs + VALU later). acc: double-buffered
        // for the interleaved prev-tile argmin.
        int ntBase = wv * 64;
        half8 bhA[4], bhB[4], blC[4];
        float csA, csB;
        float4v accA[4], accB[4];

        load_bh(bq_hi, csqq, ntBase + 0, lane, bhA, csA);
        load_bl(bq_lo, ntBase + 0, lane, blC);

        // peeled j=0: tiles 0 (no prev) and 1
        load_bh(bq_hi, csqq, ntBase + 1, lane, bhB, csB);
        tile_pipe<false>(accA, ahi, alo, bhA, blC, csA, accB, 0.f, bestd, besti);
        load_bl(bq_lo, ntBase + 1, lane, blC);
        load_bh(bq_hi, csqq, ntBase + 2, lane, bhA, csA);
        {
            float fiP = (float)((ntBase + 0) * 16) + fcol;
            tile_pipe<true>(accB, ahi, alo, bhB, blC, csB, accA, fiP, bestd, besti);
        }
        load_bl(bq_lo, ntBase + 2, lane, blC);

        for (int j = 1; j < 32; ++j) {
            int t0 = ntBase + 2 * j;
            // even phase: tile t0 (accA), argmin tile t0-1 (accB)
            load_bh(bq_hi, csqq, t0 + 1, lane, bhB, csB);
            {
                float fiP = (float)((t0 - 1) * 16) + fcol;
                tile_pipe<true>(accA, ahi, alo, bhA, blC, csA, accB, fiP, bestd, besti);
            }
            load_bl(bq_lo, t0 + 1, lane, blC);
            // odd phase: tile t0+1 (accB), argmin tile t0 (accA)
            int tn = ntBase + ((2 * j + 2) & 63);
            load_bh(bq_hi, csqq, tn, lane, bhA, csA);
            {
                float fiP = (float)(t0 * 16) + fcol;
                tile_pipe<true>(accB, ahi, alo, bhB, blC, csB, accA, fiP, bestd, besti);
            }
            load_bl(bq_lo, tn, lane, blC);
        }
        // tail: argmin of tile ntBase+63 (accB)
        {
            float fiP = (float)((ntBase + 63) * 16) + fcol;
            argmin_pair(accB, 0, fiP, bestd, besti);
            argmin_pair(accB, 2, fiP, bestd, besti);
        }

        // reduce across the 16 lanes sharing each row (low 4 lane bits)
#pragma unroll
        for (int mask = 1; mask <= 8; mask <<= 1) {
#pragma unroll
            for (int mt = 0; mt < 4; ++mt)
#pragma unroll
            for (int r = 0; r < 4; ++r) {
                float od = __shfl_xor(bestd[mt][r], mask, 64);
                float oi = __shfl_xor(besti[mt][r], mask, 64);
                if (od > bestd[mt][r] || (od == bestd[mt][r] && oi < besti[mt][r])) {
                    bestd[mt][r] = od;
                    besti[mt][r] = oi;
                }
            }
        }
        if ((lane & 15) == 0) {
            int qd = lane >> 4;
#pragma unroll
            for (int mt = 0; mt < 4; ++mt)
#pragma unroll
            for (int r = 0; r < 4; ++r) {
                int row = mt * 16 + qd * 4 + r;
                wbd[wv][row] = bestd[mt][r];
                wbi[wv][row] = besti[mt][r];
            }
        }
        __syncthreads();

        // cross-wave reduce (waves cover ascending code ranges; tie -> smaller idx)
        if (tid < TM) {
            float bd = wbd[0][tid], bi = wbi[0][tid];
#pragma unroll
            for (int w = 1; w < 4; ++w) {
                float dd = wbd[w][tid], ii = wbi[w][tid];
                if (dd > bd || (dd == bd && ii < bi)) { bd = dd; bi = ii; }
            }
            fbin[tid] = bi;
            out[OUT_ELEMS + (size_t)(r0 + tid) * NQ + q] = bi;   // index output (float)
        }
        __syncthreads();

        // residual update + commitment-loss accumulation
        {
            int row = tid >> 2, j = tid & 3;
            int bi = (int)fbin[row];
            const float* cv = cb + ((size_t)q * KCODES + bi) * DIMS + j * 4;
            float* rp = &res[row][j * 4];
#pragma unroll
            for (int t = 0; t < 8; ++t) {
                float4 c4 = *(const float4*)(cv + t * 16);
                float4 r4 = *(const float4*)(rp + t * 16);
                r4.x -= c4.x; lossacc = fmaf(r4.x, r4.x, lossacc);
                r4.y -= c4.y; lossacc = fmaf(r4.y, r4.y, lossacc);
                r4.z -= c4.z; lossacc = fmaf(r4.z, r4.z, lossacc);
                r4.w -= c4.w; lossacc = fmaf(r4.w, r4.w, lossacc);
                *(float4*)(rp + t * 16) = r4;
            }
        }
    }

    // loss reduction
    __syncthreads();
    red[tid] = lossacc;
    __syncthreads();
    for (int s = 128; s > 0; s >>= 1) {
        if (tid < s) red[tid] += red[tid + s];
        __syncthreads();
    }
    if (tid == 0) atomicAdd(loss_accum, red[0]);

    // quantized output: out = x - final_residual
    {
        int d = tid >> 1, half = (tid & 1) * 32;
        const float* src = xb + (size_t)d * SEQ + half;
        float* dst = out + (size_t)b * DIMS * SEQ + (size_t)d * SEQ + n0 + half;
#pragma unroll
        for (int t4 = 0; t4 < 8; ++t4) {
            float4 v = *(const float4*)(src + t4 * 4);
            v.x -= res[half + t4 * 4 + 0][d];
            v.y -= res[half + t4 * 4 + 1][d];
            v.z -= res[half + t4 * 4 + 2][d];
            v.w -= res[half + t4 * 4 + 3][d];
            *(float4*)(dst + t4 * 4) = v;
        }
    }
}

__global__ void finish_loss(const float* __restrict__ loss_accum, float* __restrict__ out) {
    out[OUT_ELEMS + IDX_ELEMS] = loss_accum[0] * LOSS_DIV;
}

extern "C" void kernel_launch(void* const* d_in, const int* in_sizes, int n_in,
                              void* d_out, int out_size, void* d_ws, size_t ws_size,
                              hipStream_t stream) {
    const float* x  = (const float*)d_in[0];
    const float* cb = (const float*)d_in[1];
    float* out = (float*)d_out;
    char*  ws  = (char*)d_ws;

    float*     loss_accum = (float*)ws;
    float*     csq = (float*)(ws + 256);
    _Float16*  bhi = (_Float16*)(ws + 256 + 131072);
    _Float16*  blo = (_Float16*)(ws + 256 + 131072 + FRAG_HALVES * 2);

    hipLaunchKernelGGL(prep_csq,   dim3(128),  dim3(256), 0, stream, cb, csq);
    hipLaunchKernelGGL(prep_frags, dim3(2048), dim3(256), 0, stream, cb, bhi, blo, loss_accum);
    hipLaunchKernelGGL(rvq_main,   dim3(NBLK), dim3(256), 0, stream,
                       x, cb, bhi, blo, csq, out, loss_accum);
    hipLaunchKernelGGL(finish_loss, dim3(1), dim3(1), 0, stream, loss_accum, out);
}

// Round 8
// 698.206 us; speedup vs baseline: 4.2520x; 1.7276x over previous
//
#include <hip/hip_runtime.h>

typedef _Float16 half8 __attribute__((ext_vector_type(8)));
typedef float    float4v __attribute__((ext_vector_type(4)));

#define NQ 8
#define KCODES 4096
#define DIMS 128
#define BATCH 8
#define SEQ 4096
#define ROWS (BATCH*SEQ)            // 32768
#define TM 64                       // rows per block
#define NBLK (ROWS/TM)              // 512
#define RESPAD 132                  // res row stride (floats), 16B-aligned
#define OUT_ELEMS (BATCH*DIMS*SEQ)  // 4194304
#define IDX_ELEMS (BATCH*SEQ*NQ)    // 262144
#define LOSS_DIV (1.0f/33554432.0f) // 1/(Q*B*N*D)
#define FRAG_HALVES ((size_t)NQ*4*256*64*8)   // per hi/lo: 4.19M f16 = 8 MB

// ---------------- prep: c_sq[q][k] = sum_d cb^2 ----------------
__global__ void prep_csq(const float* __restrict__ cb, float* __restrict__ csq) {
    int c = blockIdx.x * 256 + threadIdx.x;   // q*4096+k
    const float4* p = (const float4*)(cb + (size_t)c * DIMS);
    float s = 0.f;
#pragma unroll
    for (int i = 0; i < 32; ++i) {
        float4 v = p[i];
        s += v.x * v.x + v.y * v.y + v.z * v.z + v.w * v.w;
    }
    csq[c] = s;
}

// ---------------- prep: codebook -> f16 hi/lo MFMA B-fragments ----------------
// mfma_f32_16x16x32_f16 B-operand: lane l holds B[k=(l>>4)*8+j][n=l&15], j=0..7.
// Storage: frag g = ((q*4+kb)*256+nt)*64+lane at bhi/blo + g*8 halves.
__global__ void prep_frags(const float* __restrict__ cb, _Float16* __restrict__ bhi,
                           _Float16* __restrict__ blo, float* __restrict__ loss_accum) {
    int g = blockIdx.x * 256 + threadIdx.x;   // 524288 total
    if (g == 0) loss_accum[0] = 0.f;
    int lane = g & 63;
    int nt   = (g >> 6) & 255;
    int kb   = (g >> 14) & 3;
    int q    = g >> 16;
    int code = nt * 16 + (lane & 15);
    int k0   = kb * 32 + ((lane >> 4) * 8);
    const float* src = cb + ((size_t)q * KCODES + code) * DIMS + k0;
    float4 v0 = *(const float4*)(src);
    float4 v1 = *(const float4*)(src + 4);
    float f[8] = { v0.x, v0.y, v0.z, v0.w, v1.x, v1.y, v1.z, v1.w };
    half8 h, l;
#pragma unroll
    for (int j = 0; j < 8; ++j) {
        _Float16 hh = (_Float16)f[j];
        h[j] = hh;
        l[j] = (_Float16)(f[j] - (float)hh);
    }
    *(half8*)(bhi + (size_t)g * 8) = h;
    *(half8*)(blo + (size_t)g * 8) = l;
}

// ---------------- main RVQ kernel ----------------
__device__ __forceinline__ void load_b(const _Float16* __restrict__ bq_hi,
                                       const _Float16* __restrict__ bq_lo,
                                       const float* __restrict__ csqq,
                                       int nt, int lane,
                                       half8 (&bh)[4], half8 (&bl)[4], float& cs) {
#pragma unroll
    for (int kb = 0; kb < 4; ++kb) {
        size_t off = (((size_t)kb * 256 + nt) * 64 + lane) * 8;
        bh[kb] = *(const half8*)(bq_hi + off);
        bl[kb] = *(const half8*)(bq_lo + off);
    }
    cs = csqq[nt * 16 + (lane & 15)];
}

// Term-major MFMA schedule: hh(kb0..3), lh(kb0..3), hl(kb0..3), mt innermost.
// Same-acc dependence distance = 4 MFMAs everywhere; bl first consumed after
// 32 MFMAs. Both bh and bl full-tile double-buffered by the caller (no WAR).
// s_setprio(1) over the MFMA region, (0) over the VALU region: stabilizes
// anti-phase wave arbitration so one wave's argmin VALU issues in the other
// wave's MFMA-pipe shadow.
__device__ __forceinline__ void compute_tile(int nt, float fcol,
                                             const half8 (&ahi)[4][4], const half8 (&alo)[4][4],
                                             const half8 (&bh)[4], const half8 (&bl)[4], float cs,
                                             float (&bestd)[4][4], float (&besti)[4][4]) {
    float nh = -0.5f * cs;
    float4v acc[4];
#pragma unroll
    for (int mt = 0; mt < 4; ++mt) { acc[mt][0] = nh; acc[mt][1] = nh; acc[mt][2] = nh; acc[mt][3] = nh; }
    __builtin_amdgcn_s_setprio(1);
#pragma unroll
    for (int kb = 0; kb < 4; ++kb)
#pragma unroll
        for (int mt = 0; mt < 4; ++mt)
            acc[mt] = __builtin_amdgcn_mfma_f32_16x16x32_f16(ahi[mt][kb], bh[kb], acc[mt], 0, 0, 0);
#pragma unroll
    for (int kb = 0; kb < 4; ++kb)
#pragma unroll
        for (int mt = 0; mt < 4; ++mt)
            acc[mt] = __builtin_amdgcn_mfma_f32_16x16x32_f16(alo[mt][kb], bh[kb], acc[mt], 0, 0, 0);
#pragma unroll
    for (int kb = 0; kb < 4; ++kb)
#pragma unroll
        for (int mt = 0; mt < 4; ++mt)
            acc[mt] = __builtin_amdgcn_mfma_f32_16x16x32_f16(ahi[mt][kb], bl[kb], acc[mt], 0, 0, 0);
    __builtin_amdgcn_s_setprio(0);

    // key = dot - csq/2; argMAX == argmin(csq - 2*dot); strict > keeps first index
    float fidx = (float)(nt * 16) + fcol;
#pragma unroll
    for (int mt = 0; mt < 4; ++mt)
#pragma unroll
        for (int r = 0; r < 4; ++r) {
            float key = acc[mt][r];
            if (key > bestd[mt][r]) { bestd[mt][r] = key; besti[mt][r] = fidx; }
        }
}

__launch_bounds__(256, 2)
__global__ void rvq_main(const float* __restrict__ x, const float* __restrict__ cb,
                         const _Float16* __restrict__ bhi, const _Float16* __restrict__ blo,
                         const float* __restrict__ csq,
                         float* __restrict__ out, float* __restrict__ loss_accum) {
    __shared__ float res[TM][RESPAD];   // residual, row-major fp32
    __shared__ float wbd[4][TM];        // per-wave best key
    __shared__ float wbi[4][TM];        // per-wave best idx (as float)
    __shared__ float fbin[TM];          // final best idx per row
    __shared__ float red[256];

    int tid  = threadIdx.x;
    int lane = tid & 63;
    int wv   = tid >> 6;
    int r0   = blockIdx.x * TM;
    int b    = r0 >> 12;                // / SEQ
    int n0   = r0 & (SEQ - 1);
    const float* xb = x + (size_t)b * DIMS * SEQ + n0;
    float fcol = (float)(lane & 15);

    // load x[b][d][n0..n0+63] into res[n][d]
    {
        int d = tid >> 1, half = (tid & 1) * 32;
        const float* src = xb + (size_t)d * SEQ + half;
#pragma unroll
        for (int t4 = 0; t4 < 8; ++t4) {
            float4 v = *(const float4*)(src + t4 * 4);
            res[half + t4 * 4 + 0][d] = v.x;
            res[half + t4 * 4 + 1][d] = v.y;
            res[half + t4 * 4 + 2][d] = v.z;
            res[half + t4 * 4 + 3][d] = v.w;
        }
    }

    float lossacc = 0.f;

    for (int q = 0; q < NQ; ++q) {
        __syncthreads();   // res stable

        // build A fragments (hi/lo) in registers/AGPRs
        half8 ahi[4][4], alo[4][4];
#pragma unroll
        for (int mt = 0; mt < 4; ++mt)
#pragma unroll
        for (int kb = 0; kb < 4; ++kb) {
            int row = mt * 16 + (lane & 15);
            int k0  = kb * 32 + (lane >> 4) * 8;
            float4 v0 = *(const float4*)&res[row][k0];
            float4 v1 = *(const float4*)&res[row][k0 + 4];
            float f[8] = { v0.x, v0.y, v0.z, v0.w, v1.x, v1.y, v1.z, v1.w };
            half8 h, l;
#pragma unroll
            for (int j = 0; j < 8; ++j) {
                _Float16 hh = (_Float16)f[j];
                h[j] = hh;
                l[j] = (_Float16)(f[j] - (float)hh);
            }
            ahi[mt][kb] = h;
            alo[mt][kb] = l;
        }

        const _Float16* bq_hi = bhi + (size_t)q * (4 * 256 * 64 * 8);
        const _Float16* bq_lo = blo + (size_t)q * (4 * 256 * 64 * 8);
        const float*    csqq  = csq + q * KCODES;

        float bestd[4][4], besti[4][4];
#pragma unroll
        for (int mt = 0; mt < 4; ++mt)
#pragma unroll
        for (int r = 0; r < 4; ++r) { bestd[mt][r] = -3.4e38f; besti[mt][r] = 0.f; }

        // each wave owns n-tiles [wv*64, wv*64+64); full double-buffered B prefetch
        int ntBase = wv * 64;
        half8 bh0[4], bl0[4], bh1[4], bl1[4];
        float cs0, cs1;
        load_b(bq_hi, bq_lo, csqq, ntBase, lane, bh0, bl0, cs0);

        // Phase stagger: odd waves burn ~40 throwaway MFMAs (~190 cyc, about one
        // VALU-phase) so their MFMA phase anti-aligns with even waves' VALU phase.
        // accD is preamble-local (no persistent registers). Kept live via
        // fmaf(0, ., lossacc) — not foldable without fast-math.
        if (wv & 1) {
            float4v accD[4];
            float nh = -0.5f * cs0;
#pragma unroll
            for (int mt = 0; mt < 4; ++mt) { accD[mt][0] = nh; accD[mt][1] = nh; accD[mt][2] = nh; accD[mt][3] = nh; }
            __builtin_amdgcn_s_setprio(1);
#pragma unroll
            for (int kb = 0; kb < 4; ++kb)
#pragma unroll
                for (int mt = 0; mt < 4; ++mt)
                    accD[mt] = __builtin_amdgcn_mfma_f32_16x16x32_f16(ahi[mt][kb], bh0[kb], accD[mt], 0, 0, 0);
#pragma unroll
            for (int kb = 0; kb < 4; ++kb)
#pragma unroll
                for (int mt = 0; mt < 4; ++mt)
                    accD[mt] = __builtin_amdgcn_mfma_f32_16x16x32_f16(alo[mt][kb], bh0[kb], accD[mt], 0, 0, 0);
#pragma unroll
            for (int kb = 0; kb < 2; ++kb)
#pragma unroll
                for (int mt = 0; mt < 4; ++mt)
                    accD[mt] = __builtin_amdgcn_mfma_f32_16x16x32_f16(ahi[mt][kb], bl0[kb], accD[mt], 0, 0, 0);
            __builtin_amdgcn_s_setprio(0);
            lossacc = fmaf(0.0f, (accD[0][0] + accD[1][0]) + (accD[2][0] + accD[3][0]), lossacc);
        }

        for (int i = 0; i < 64; i += 2) {
            load_b(bq_hi, bq_lo, csqq, ntBase + i + 1, lane, bh1, bl1, cs1);
            compute_tile(ntBase + i, fcol, ahi, alo, bh0, bl0, cs0, bestd, besti);
            load_b(bq_hi, bq_lo, csqq, ntBase + ((i + 2) & 63), lane, bh0, bl0, cs0);
            compute_tile(ntBase + i + 1, fcol, ahi, alo, bh1, bl1, cs1, bestd, besti);
        }

        // reduce across the 16 lanes sharing each row (low 4 lane bits)
#pragma unroll
        for (int mask = 1; mask <= 8; mask <<= 1) {
#pragma unroll
            for (int mt = 0; mt < 4; ++mt)
#pragma unroll
            for (int r = 0; r < 4; ++r) {
                float od = __shfl_xor(bestd[mt][r], mask, 64);
                float oi = __shfl_xor(besti[mt][r], mask, 64);
                if (od > bestd[mt][r] || (od == bestd[mt][r] && oi < besti[mt][r])) {
                    bestd[mt][r] = od;
                    besti[mt][r] = oi;
                }
            }
        }
        if ((lane & 15) == 0) {
            int qd = lane >> 4;
#pragma unroll
            for (int mt = 0; mt < 4; ++mt)
#pragma unroll
            for (int r = 0; r < 4; ++r) {
                int row = mt * 16 + qd * 4 + r;
                wbd[wv][row] = bestd[mt][r];
                wbi[wv][row] = besti[mt][r];
            }
        }
        __syncthreads();

        // cross-wave reduce (waves cover ascending code ranges; tie -> smaller idx)
        if (tid < TM) {
            float bd = wbd[0][tid], bi = wbi[0][tid];
#pragma unroll
            for (int w = 1; w < 4; ++w) {
                float dd = wbd[w][tid], ii = wbi[w][tid];
                if (dd > bd || (dd == bd && ii < bi)) { bd = dd; bi = ii; }
            }
            fbin[tid] = bi;
            out[OUT_ELEMS + (size_t)(r0 + tid) * NQ + q] = bi;   // index output (float)
        }
        __syncthreads();

        // residual update + commitment-loss accumulation
        {
            int row = tid >> 2, j = tid & 3;
            int bi = (int)fbin[row];
            const float* cv = cb + ((size_t)q * KCODES + bi) * DIMS + j * 4;
            float* rp = &res[row][j * 4];
#pragma unroll
            for (int t = 0; t < 8; ++t) {
                float4 c4 = *(const float4*)(cv + t * 16);
                float4 r4 = *(const float4*)(rp + t * 16);
                r4.x -= c4.x; lossacc = fmaf(r4.x, r4.x, lossacc);
                r4.y -= c4.y; lossacc = fmaf(r4.y, r4.y, lossacc);
                r4.z -= c4.z; lossacc = fmaf(r4.z, r4.z, lossacc);
                r4.w -= c4.w; lossacc = fmaf(r4.w, r4.w, lossacc);
                *(float4*)(rp + t * 16) = r4;
            }
        }
    }

    // loss reduction
    __syncthreads();
    red[tid] = lossacc;
    __syncthreads();
    for (int s = 128; s > 0; s >>= 1) {
        if (tid < s) red[tid] += red[tid + s];
        __syncthreads();
    }
    if (tid == 0) atomicAdd(loss_accum, red[0]);

    // quantized output: out = x - final_residual
    {
        int d = tid >> 1, half = (tid & 1) * 32;
        const float* src = xb + (size_t)d * SEQ + half;
        float* dst = out + (size_t)b * DIMS * SEQ + (size_t)d * SEQ + n0 + half;
#pragma unroll
        for (int t4 = 0; t4 < 8; ++t4) {
            float4 v = *(const float4*)(src + t4 * 4);
            v.x -= res[half + t4 * 4 + 0][d];
            v.y -= res[half + t4 * 4 + 1][d];
            v.z -= res[half + t4 * 4 + 2][d];
            v.w -= res[half + t4 * 4 + 3][d];
            *(float4*)(dst + t4 * 4) = v;
        }
    }
}

__global__ void finish_loss(const float* __restrict__ loss_accum, float* __restrict__ out) {
    out[OUT_ELEMS + IDX_ELEMS] = loss_accum[0] * LOSS_DIV;
}

extern "C" void kernel_launch(void* const* d_in, const int* in_sizes, int n_in,
                              void* d_out, int out_size, void* d_ws, size_t ws_size,
                              hipStream_t stream) {
    const float* x  = (const float*)d_in[0];
    const float* cb = (const float*)d_in[1];
    float* out = (float*)d_out;
    char*  ws  = (char*)d_ws;

    float*     loss_accum = (float*)ws;
    float*     csq = (float*)(ws + 256);
    _Float16*  bhi = (_Float16*)(ws + 256 + 131072);
    _Float16*  blo = (_Float16*)(ws + 256 + 131072 + FRAG_HALVES * 2);

    hipLaunchKernelGGL(prep_csq,   dim3(128),  dim3(256), 0, stream, cb, csq);
    hipLaunchKernelGGL(prep_frags, dim3(2048), dim3(256), 0, stream, cb, bhi, blo, loss_accum);
    hipLaunchKernelGGL(rvq_main,   dim3(NBLK), dim3(256), 0, stream,
                       x, cb, bhi, blo, csq, out, loss_accum);
    hipLaunchKernelGGL(finish_loss, dim3(1), dim3(1), 0, stream, loss_accum, out);
}